// Round 1
// baseline (838.454 us; speedup 1.0000x reference)
//
#include <hip/hip_runtime.h>

#define N 2048
#define D 128
#define BB 16

// ---------------------------------------------------------------------------
// Kernel 1: S = Q @ K^T (raw scores), written to the attn region of d_out.
// Tile: 64 (i) x 64 (j) per workgroup, full D=128 in LDS.
// LDS layout: row-major [row][d], XOR-swizzled in float4 granules:
//   phys_d4 = d4 ^ ((row>>2) & 7)  -> keeps b128 reads <=2-way bank conflict.
// Each thread: 4x4 output tile, float4-vectorized accumulation over d.
// ---------------------------------------------------------------------------
__global__ __launch_bounds__(256) void qk_kernel(const float* __restrict__ q,
                                                 const float* __restrict__ k,
                                                 float* __restrict__ s) {
    __shared__ float Qs[64 * 128];
    __shared__ float Ks[64 * 128];
    const int t  = threadIdx.x;
    const int b  = blockIdx.z;
    const int ib = blockIdx.y * 64;
    const int jb = blockIdx.x * 64;
    const float* qp = q + ((size_t)b * N + ib) * D;
    const float* kp = k + ((size_t)b * N + jb) * D;

    // Stage Q and K tiles (64x128 each), coalesced float4 global reads.
    #pragma unroll
    for (int c = 0; c < 8; ++c) {
        int flat4 = c * 256 + t;        // 2048 float4s per tile
        int row   = flat4 >> 5;         // 32 float4 per row
        int d4    = flat4 & 31;
        int pd    = d4 ^ ((row >> 2) & 7);
        float4 qv = *(const float4*)(qp + (size_t)row * D + 4 * d4);
        float4 kv = *(const float4*)(kp + (size_t)row * D + 4 * d4);
        *(float4*)(Qs + row * 128 + 4 * pd) = qv;
        *(float4*)(Ks + row * 128 + 4 * pd) = kv;
    }
    __syncthreads();

    const int i0 = (t >> 4) << 2;   // 0..60 step 4
    const int j0 = (t & 15) << 2;   // 0..60 step 4
    const int mq = (i0 >> 2) & 7;   // swizzle mask (same for rows i0..i0+3)
    const int mk = (j0 >> 2) & 7;

    float4 acc[4][4];
    #pragma unroll
    for (int r = 0; r < 4; ++r)
        #pragma unroll
        for (int c = 0; c < 4; ++c) acc[r][c] = make_float4(0.f, 0.f, 0.f, 0.f);

    for (int d4 = 0; d4 < 32; ++d4) {
        float4 qv[4], kv[4];
        const int qoff = 4 * (d4 ^ mq);
        const int koff = 4 * (d4 ^ mk);
        #pragma unroll
        for (int r = 0; r < 4; ++r) qv[r] = *(const float4*)(Qs + (i0 + r) * 128 + qoff);
        #pragma unroll
        for (int c = 0; c < 4; ++c) kv[c] = *(const float4*)(Ks + (j0 + c) * 128 + koff);
        #pragma unroll
        for (int r = 0; r < 4; ++r)
            #pragma unroll
            for (int c = 0; c < 4; ++c) {
                acc[r][c].x += qv[r].x * kv[c].x;
                acc[r][c].y += qv[r].y * kv[c].y;
                acc[r][c].z += qv[r].z * kv[c].z;
                acc[r][c].w += qv[r].w * kv[c].w;
            }
    }

    // Epilogue: horizontal sums, coalesced float4 store of raw scores.
    #pragma unroll
    for (int r = 0; r < 4; ++r) {
        float4 o;
        o.x = acc[r][0].x + acc[r][0].y + acc[r][0].z + acc[r][0].w;
        o.y = acc[r][1].x + acc[r][1].y + acc[r][1].z + acc[r][1].w;
        o.z = acc[r][2].x + acc[r][2].y + acc[r][2].z + acc[r][2].w;
        o.w = acc[r][3].x + acc[r][3].y + acc[r][3].z + acc[r][3].w;
        *(float4*)(s + ((size_t)b * N + ib + i0 + r) * N + jb + j0) = o;
    }
}

// ---------------------------------------------------------------------------
// Kernel 2: in-place row softmax over attn. One workgroup per (b, row).
// 256 threads x 8 floats (2 float4) each = 2048.
// ---------------------------------------------------------------------------
__global__ __launch_bounds__(256) void softmax_kernel(float* __restrict__ attn) {
    const int t = threadIdx.x;
    float* row = attn + ((size_t)blockIdx.y * N + blockIdx.x) * N;

    float4 v0 = *(const float4*)(row + 4 * t);
    float4 v1 = *(const float4*)(row + 4 * t + 1024);

    float m = fmaxf(fmaxf(fmaxf(v0.x, v0.y), fmaxf(v0.z, v0.w)),
                    fmaxf(fmaxf(v1.x, v1.y), fmaxf(v1.z, v1.w)));
    #pragma unroll
    for (int off = 32; off > 0; off >>= 1) m = fmaxf(m, __shfl_xor(m, off));

    __shared__ float redm[4];
    __shared__ float reds[4];
    if ((t & 63) == 0) redm[t >> 6] = m;
    __syncthreads();
    m = fmaxf(fmaxf(redm[0], redm[1]), fmaxf(redm[2], redm[3]));

    float4 e0, e1;
    e0.x = __expf(v0.x - m); e0.y = __expf(v0.y - m);
    e0.z = __expf(v0.z - m); e0.w = __expf(v0.w - m);
    e1.x = __expf(v1.x - m); e1.y = __expf(v1.y - m);
    e1.z = __expf(v1.z - m); e1.w = __expf(v1.w - m);

    float sum = e0.x + e0.y + e0.z + e0.w + e1.x + e1.y + e1.z + e1.w;
    #pragma unroll
    for (int off = 32; off > 0; off >>= 1) sum += __shfl_xor(sum, off);
    if ((t & 63) == 0) reds[t >> 6] = sum;
    __syncthreads();
    sum = reds[0] + reds[1] + reds[2] + reds[3];

    const float inv = 1.0f / sum;
    e0.x *= inv; e0.y *= inv; e0.z *= inv; e0.w *= inv;
    e1.x *= inv; e1.y *= inv; e1.z *= inv; e1.w *= inv;
    *(float4*)(row + 4 * t)        = e0;
    *(float4*)(row + 4 * t + 1024) = e1;
}

// ---------------------------------------------------------------------------
// Kernel 3: O = P @ V. Tile: 64 (i) x 128 (d) per workgroup, loop j in 64s.
// P staged [64][65] (pad +1: scalar reads, broadcast across lanes).
// V staged [64][132] (pad +4: keeps b128 reads 16B-aligned, <=2-way banks).
// Each thread: 4 rows x 16 cols (two float4 column groups, d0 and d0+64).
// ---------------------------------------------------------------------------
__global__ __launch_bounds__(256) void pv_kernel(const float* __restrict__ p,
                                                 const float* __restrict__ v,
                                                 float* __restrict__ o) {
    __shared__ float Ps[64 * 65];
    __shared__ float Vs[64 * 132];
    const int t  = threadIdx.x;
    const int b  = blockIdx.y;
    const int ib = blockIdx.x * 64;
    const float* pp = p + ((size_t)b * N + ib) * N;
    const float* vp = v + (size_t)b * N * D;

    const int i0 = (t >> 4) << 2;
    const int d0 = (t & 15) << 2;

    float4 acc[4][2];
    #pragma unroll
    for (int r = 0; r < 4; ++r) {
        acc[r][0] = make_float4(0.f, 0.f, 0.f, 0.f);
        acc[r][1] = make_float4(0.f, 0.f, 0.f, 0.f);
    }

    for (int jt = 0; jt < 32; ++jt) {
        __syncthreads();  // protect LDS reuse from previous iteration
        // Stage P tile 64x64 (attn rows ib..ib+63, cols jt*64..+63)
        #pragma unroll
        for (int c = 0; c < 4; ++c) {
            int flat4 = c * 256 + t;    // 1024 float4s
            int row   = flat4 >> 4;     // 16 float4 per row
            int j4    = flat4 & 15;
            float4 pv4 = *(const float4*)(pp + (size_t)row * N + jt * 64 + 4 * j4);
            float* dst = Ps + row * 65 + 4 * j4;
            dst[0] = pv4.x; dst[1] = pv4.y; dst[2] = pv4.z; dst[3] = pv4.w;
        }
        // Stage V tile 64x128
        #pragma unroll
        for (int c = 0; c < 8; ++c) {
            int flat4 = c * 256 + t;    // 2048 float4s
            int row   = flat4 >> 5;
            int d4    = flat4 & 31;
            *(float4*)(Vs + row * 132 + 4 * d4) =
                *(const float4*)(vp + (size_t)(jt * 64 + row) * D + 4 * d4);
        }
        __syncthreads();

        for (int j = 0; j < 64; ++j) {
            float4 vv0 = *(const float4*)(Vs + j * 132 + d0);
            float4 vv1 = *(const float4*)(Vs + j * 132 + d0 + 64);
            #pragma unroll
            for (int r = 0; r < 4; ++r) {
                float pr = Ps[(i0 + r) * 65 + j];
                acc[r][0].x += pr * vv0.x; acc[r][0].y += pr * vv0.y;
                acc[r][0].z += pr * vv0.z; acc[r][0].w += pr * vv0.w;
                acc[r][1].x += pr * vv1.x; acc[r][1].y += pr * vv1.y;
                acc[r][1].z += pr * vv1.z; acc[r][1].w += pr * vv1.w;
            }
        }
    }

    #pragma unroll
    for (int r = 0; r < 4; ++r) {
        *(float4*)(o + ((size_t)b * N + ib + i0 + r) * D + d0)      = acc[r][0];
        *(float4*)(o + ((size_t)b * N + ib + i0 + r) * D + d0 + 64) = acc[r][1];
    }
}

extern "C" void kernel_launch(void* const* d_in, const int* in_sizes, int n_in,
                              void* d_out, int out_size, void* d_ws, size_t ws_size,
                              hipStream_t stream) {
    const float* q = (const float*)d_in[0];
    const float* k = (const float*)d_in[1];
    const float* v = (const float*)d_in[2];
    float* out  = (float*)d_out;                    // [16,2048,128]
    float* attn = out + (size_t)BB * N * D;         // [16,2048,2048]

    qk_kernel<<<dim3(N / 64, N / 64, BB), 256, 0, stream>>>(q, k, attn);
    softmax_kernel<<<dim3(N, BB), 256, 0, stream>>>(attn);
    pv_kernel<<<dim3(N / 64, BB), 256, 0, stream>>>(attn, v, out);
}